// Round 15
// baseline (480.954 us; speedup 1.0000x reference)
//
#include <hip/hip_runtime.h>
#include <hip/hip_bf16.h>

#define B_SZ 4
#define N_INST 2048
#define D_MODEL 512
#define S_TOT 2049          // N+1 (cls prepended)
#define NH 8
#define HD 64
#define VB 8                // virtual batches = 2 branches x 4 batch
#define VROWS (VB*S_TOT)    // 16392
#define NCHUNK 16           // split-K chunks for row-0 attention
#define SCLOG2 0.18033688011112042f   // 0.125 * log2(e) — log2-domain score scale

typedef __attribute__((ext_vector_type(4))) float f32x4;
typedef __attribute__((ext_vector_type(8))) short bf16x8;

__device__ __forceinline__ float gelu_exact(float x){ return 0.5f*x*(1.f+erff(x*0.70710678118654752f)); }
__device__ __forceinline__ float fexp2(float x){ return __builtin_amdgcn_exp2f(x); } // raw v_exp_f32
__device__ __forceinline__ unsigned short f2bf(float x){
  unsigned int u = __float_as_uint(x);
  u += 0x7fffu + ((u>>16)&1u);
  return (unsigned short)(u>>16);
}
__device__ __forceinline__ float bfval(unsigned short u){ return __uint_as_float(((unsigned int)u)<<16); }
__device__ __forceinline__ unsigned int pk2(unsigned short lo, unsigned short hi){
  return (unsigned int)lo | ((unsigned int)hi << 16);
}
__device__ __forceinline__ unsigned short ext16(unsigned int u, int hi){
  return (unsigned short)(hi ? (u>>16) : (u & 0xffffu));
}

#define GLOAD16(gp, lp) __builtin_amdgcn_global_load_lds( \
    (const __attribute__((address_space(1))) void*)(gp), \
    (__attribute__((address_space(3))) void*)(lp), 16, 0, 0)

// ---------------------------------------------------------------------------
// One-time transpose: W0T[k][h] = W0[h][k]   (64x512 -> 512x64, fp32)
// ---------------------------------------------------------------------------
__global__ __launch_bounds__(256) void transpose_w0_kernel(
    const float* __restrict__ W0, float* __restrict__ W0T) {
  int i = blockIdx.x*256 + threadIdx.x;
  if (i < 64*512){
    int h = i >> 9, k = i & 511;
    W0T[k*64 + h] = W0[i];
  }
}

// ---------------------------------------------------------------------------
// Gating MLP (fp32: the w<0.5 mask is a threshold — bf16 risks branch flips).
// ---------------------------------------------------------------------------
__global__ __launch_bounds__(64) void aw_weight_kernel(
    const float* __restrict__ x,
    const float* __restrict__ W0T, const float* __restrict__ b0,
    const float* __restrict__ W1, const float* __restrict__ b1,
    const float* __restrict__ W2, const float* __restrict__ b2,
    float* __restrict__ weight) {
  int inst = blockIdx.x;
  int h = threadIdx.x;
  __shared__ float xs[512];
  __shared__ float hs[64];
  const float* xp = x + (size_t)inst*D_MODEL;
  for (int i=h;i<512;i+=64) xs[i] = xp[i];
  __syncthreads();
  float acc = b0[h];
  const float* w0c = W0T + h;
  #pragma unroll 16
  for (int k=0;k<512;k++)
    acc = fmaf(xs[k], w0c[k*64], acc);
  hs[h] = gelu_exact(acc);
  __syncthreads();
  const float4* w1 = (const float4*)(W1 + (size_t)h*64);
  float acc2 = b1[h];
  #pragma unroll
  for (int k4=0;k4<16;k4++){
    float4 u = w1[k4]; int k = k4*4;
    acc2 += hs[k+0]*u.x + hs[k+1]*u.y + hs[k+2]*u.z + hs[k+3]*u.w;
  }
  float h2 = gelu_exact(acc2);
  float p = h2 * W2[h];
  #pragma unroll
  for (int o=32;o;o>>=1) p += __shfl_down(p, o);
  if (h==0){
    float s = p + b2[0];
    weight[inst] = 1.f/(1.f+expf(-s));
  }
}

// ---------------------------------------------------------------------------
// Split fp32 -> (hi, lo) bf16 pair.
// ---------------------------------------------------------------------------
__global__ __launch_bounds__(256) void split_kernel(
    const float* __restrict__ w, unsigned short* __restrict__ hi,
    unsigned short* __restrict__ lo, int n) {
  int i = blockIdx.x*256 + threadIdx.x;
  if (i < n){
    float v = w[i];
    unsigned short h = f2bf(v);
    hi[i] = h;
    lo[i] = f2bf(v - bfval(h));
  }
}

// ---------------------------------------------------------------------------
// Compaction per virtual batch vb = branch*4 + b (slot0 = cls).
// ---------------------------------------------------------------------------
__global__ __launch_bounds__(256) void compact_kernel(
    const float* __restrict__ weight,
    int* __restrict__ idx, int* __restrict__ cnt) {
  int vb = blockIdx.x;
  int b = vb & 3, branch = vb >> 2;
  int t = threadIdx.x;
  int lane = t & 63, wv = t >> 6;
  __shared__ int wsum[4];
  __shared__ int base_s;
  if (t==0){ idx[vb*S_TOT] = 0; base_s = 1; }
  __syncthreads();
  for (int c0=0; c0<N_INST; c0+=256){
    int n = c0 + t;
    float w = weight[b*N_INST + n];
    bool neg = (w < 0.5f);
    bool val = (branch==0) ? neg : !neg;
    unsigned long long m = __ballot(val);
    int prefix = __popcll(m & ((1ull<<lane)-1ull));
    if (lane==0) wsum[wv] = __popcll(m);
    __syncthreads();
    int wbase = 0;
    #pragma unroll
    for (int i=0;i<4;i++) if (i<wv) wbase += wsum[i];
    int total = wsum[0]+wsum[1]+wsum[2]+wsum[3];
    int mybase = base_s;
    if (val) idx[vb*S_TOT + mybase + wbase + prefix] = n + 1;
    __syncthreads();
    if (t==0) base_s += total;
    __syncthreads();
  }
  if (t==0) cnt[vb] = base_s;
}

// ---------------------------------------------------------------------------
// Build compacted z = LN(scale*seq[idx]) -> hi/lo bf16 pair. grid = VROWS.
// ---------------------------------------------------------------------------
__global__ __launch_bounds__(256) void build_z_kernel(
    const float* __restrict__ x, const float* __restrict__ weight,
    const float* __restrict__ cls, const float* __restrict__ g, const float* __restrict__ be,
    const int* __restrict__ idx, const int* __restrict__ cnt,
    unsigned short* __restrict__ Zh, unsigned short* __restrict__ Zl) {
  int row = blockIdx.x;
  int vb = row / S_TOT, slot = row % S_TOT;
  if (slot >= cnt[vb]) return;
  int b = vb & 3, branch = vb >> 2;
  int t = threadIdx.x;
  __shared__ float v[512];
  __shared__ float red[16];
  int pos = idx[vb*S_TOT + slot];
  float scale = 1.f;
  const float* src = cls;
  if (pos != 0){
    float w = weight[b*N_INST + (pos-1)];
    scale = (branch==0) ? powf(w, 1.5f) : powf(w, 2.0f/3.0f);
    src = x + ((size_t)b*N_INST + (pos-1))*D_MODEL;
  }
  float s1=0.f, s2=0.f;
  for (int i=t;i<512;i+=256){
    float val = src[i];
    if (pos != 0) val *= scale;
    v[i]=val; s1+=val; s2+=val*val;
  }
  __syncthreads();
  #pragma unroll
  for (int o=32;o;o>>=1){ s1+=__shfl_down(s1,o); s2+=__shfl_down(s2,o); }
  if ((t&63)==0){ red[t>>6]=s1; red[8+(t>>6)]=s2; }
  __syncthreads();
  s1 = red[0]+red[1]+red[2]+red[3];
  s2 = red[8]+red[9]+red[10]+red[11];
  float mean = s1 * (1.f/512.f);
  float var  = s2 * (1.f/512.f) - mean*mean;
  float rn = rsqrtf(var + 1e-5f);
  size_t ro = (size_t)row*512;
  for (int i=t;i<512;i+=256){
    float o = (v[i]-mean)*rn*g[i] + be[i];
    unsigned short hbits = f2bf(o);
    Zh[ro+i] = hbits;
    Zl[ro+i] = f2bf(o - bfval(hbits));
  }
}

// out = LN((Zh+Zl) + T2) rowwise -> hi/lo bf16 pair (the a1 operand)
__global__ __launch_bounds__(256) void add_ln_kernel(
    const unsigned short* __restrict__ Zh, const unsigned short* __restrict__ Zl,
    const float* __restrict__ T2,
    const float* __restrict__ g, const float* __restrict__ be,
    const int* __restrict__ cnt,
    unsigned short* __restrict__ Ah, unsigned short* __restrict__ Al) {
  int row = blockIdx.x;
  if ((row % S_TOT) >= cnt[row / S_TOT]) return;
  int t = threadIdx.x;
  __shared__ float v[512];
  __shared__ float red[16];
  size_t ro = (size_t)row*512;
  float s1=0.f, s2=0.f;
  for (int i=t;i<512;i+=256){
    float val = bfval(Zh[ro+i]) + bfval(Zl[ro+i]) + T2[ro+i];
    v[i]=val; s1+=val; s2+=val*val;
  }
  __syncthreads();
  #pragma unroll
  for (int o=32;o;o>>=1){ s1+=__shfl_down(s1,o); s2+=__shfl_down(s2,o); }
  if ((t&63)==0){ red[t>>6]=s1; red[8+(t>>6)]=s2; }
  __syncthreads();
  s1 = red[0]+red[1]+red[2]+red[3];
  s2 = red[8]+red[9]+red[10]+red[11];
  float mean = s1 * (1.f/512.f);
  float var  = s2 * (1.f/512.f) - mean*mean;
  float rn = rsqrtf(var + 1e-5f);
  for (int i=t;i<512;i+=256){
    float o = (v[i]-mean)*rn*g[i] + be[i];
    unsigned short hbits = f2bf(o);
    Ah[ro+i] = hbits;
    Al[ro+i] = f2bf(o - bfval(hbits));
  }
}

// ---------------------------------------------------------------------------
// MFMA GEMM (bf16 hi/lo 3-pass): C[M,N] = (Ah+Al)[M,512] @ (Wh+Wl)[N,512]^T + bias.
// obf16=1 -> write bf16 (ushort, stride N); else fp32.
// ---------------------------------------------------------------------------
__global__ __launch_bounds__(256) void mfma_gemm_kernel(
    const unsigned short* __restrict__ Ahg, const unsigned short* __restrict__ Alg,
    const unsigned short* __restrict__ Whg, const unsigned short* __restrict__ Wlg,
    const float* __restrict__ bias, void* __restrict__ Cout,
    int M, int N, const int* __restrict__ cnt, int obf16) {
  int t = threadIdx.x;
  int bm = blockIdx.y*64, bn = blockIdx.x*64;
  {
    int r = bm + (t>>2);
    bool ok = (r < M) && ((r % S_TOT) < cnt[r / S_TOT]);
    if (__syncthreads_or(ok ? 1 : 0) == 0) return;
  }
  __shared__ unsigned short Ahs[64*64], Als[64*64], Whs[64*64], Wls[64*64];
  int lane = t & 63, w = t >> 6;
  int l15 = lane & 15, l4 = lane >> 4;

  const unsigned short* src;
  unsigned short* dst;
  if      (w == 0){ src = Ahg; dst = Ahs; }
  else if (w == 1){ src = Alg; dst = Als; }
  else if (w == 2){ src = Whg; dst = Whs; }
  else            { src = Wlg; dst = Wls; }
  int tb  = (w < 2) ? bm : bn;
  int lim = (w < 2) ? M  : N;
  int lrow = lane >> 3;
  int lg   = lane & 7;
  const unsigned short* gp[8];
  #pragma unroll
  for (int i=0;i<8;i++){
    int row_l = i*8 + lrow;
    int rg = tb + row_l; if (rg >= lim) rg = lim-1;
    gp[i] = src + (size_t)rg*512 + (size_t)((lg ^ (row_l&7))*8);
  }

  f32x4 acc[4];
  #pragma unroll
  for (int mt=0;mt<4;mt++) acc[mt] = (f32x4){0.f,0.f,0.f,0.f};

  for (int ch=0; ch<8; ch++){
    __syncthreads();
    #pragma unroll
    for (int i=0;i<8;i++)
      GLOAD16(gp[i] + ch*64, dst + i*512);
    __syncthreads();
    #pragma unroll
    for (int ks=0; ks<2; ks++){
      int wrow = w*16 + l15;
      int wgs = (ks*4 + l4) ^ (wrow & 7);
      bf16x8 wh = *(const bf16x8*)&Whs[wrow*64 + wgs*8];
      bf16x8 wl = *(const bf16x8*)&Wls[wrow*64 + wgs*8];
      #pragma unroll
      for (int mt=0;mt<4;mt++){
        int arow = mt*16 + l15;
        int ags = (ks*4 + l4) ^ (arow & 7);
        bf16x8 ah = *(const bf16x8*)&Ahs[arow*64 + ags*8];
        bf16x8 al = *(const bf16x8*)&Als[arow*64 + ags*8];
        acc[mt] = __builtin_amdgcn_mfma_f32_16x16x32_bf16(ah, wh, acc[mt], 0,0,0);
        acc[mt] = __builtin_amdgcn_mfma_f32_16x16x32_bf16(ah, wl, acc[mt], 0,0,0);
        acc[mt] = __builtin_amdgcn_mfma_f32_16x16x32_bf16(al, wh, acc[mt], 0,0,0);
      }
    }
  }
  int ncol = bn + w*16 + l15;
  float bv = bias[ncol];
  #pragma unroll
  for (int mt=0;mt<4;mt++){
    #pragma unroll
    for (int r=0;r<4;r++){
      int mrow = bm + mt*16 + l4*4 + r;
      bool ok = (mrow < M) && ((mrow % S_TOT) < cnt[mrow / S_TOT]);
      if (ok){
        float v = acc[mt][r] + bv;
        if (obf16) ((unsigned short*)Cout)[(size_t)mrow*N + ncol] = f2bf(v);
        else       ((float*)Cout)[(size_t)mrow*N + ncol] = v;
      }
    }
  }
}

// ---------------------------------------------------------------------------
// MFMA flash attention (layer 0), bf16 QKV (stride 1536), vb = blockIdx.z.
// 64-query tile, log2-domain softmax (raw v_exp_f32). Staging is software-
// pipelined: tile k+1's K/V global loads are issued right after the second
// barrier so their latency overlaps tile k's compute (the loads live in
// VGPRs; the vmcnt drain at the next barrier then finds them complete).
// ---------------------------------------------------------------------------
__global__ __launch_bounds__(256) void flash_attn_kernel(
    const unsigned short* __restrict__ qkv, const int* __restrict__ cnt,
    unsigned short* __restrict__ Oh, unsigned short* __restrict__ Ol) {
  int vb = blockIdx.z, h = blockIdx.y;
  int cb = cnt[vb];
  int S0 = blockIdx.x * 64;
  if (S0 >= cb) return;
  int t = threadIdx.x;
  int lane = t & 63, w = t >> 6;
  int l15 = lane & 15, l4 = lane >> 4;

  __shared__ unsigned short Kbf[64*64];
  __shared__ unsigned short Vt[64*64];
  __shared__ unsigned short Pbuf[4][16*64];

  const unsigned short* basep = qkv + (size_t)(vb*S_TOT)*1536;

  int qg = S0 + w*16 + l15;
  int qr = (qg < cb) ? qg : 0;
  const unsigned short* qp = basep + (size_t)qr*1536 + h*64;
  bf16x8 Qf[2];
  Qf[0] = *(const bf16x8*)(qp + l4*8);
  Qf[1] = *(const bf16x8*)(qp + 32 + l4*8);

  float m_run = -1e30f, l_run = 0.f;
  f32x4 accO[4];
  #pragma unroll
  for (int mt=0;mt<4;mt++) accO[mt] = (f32x4){0.f,0.f,0.f,0.f};

  unsigned int* Ku = (unsigned int*)Kbf;
  unsigned int* Vu = (unsigned int*)Vt;

  // staging registers + fixed per-thread mapping
  uint4 kA, kB, vA, vC;
  int kkey = t >> 2;            // K: key slot (0..63)
  int kdo  = (t & 3) * 16;      // K: dim offset
  int vkp2 = t & 31;            // V: key-pair index
  int vd8  = t >> 5;            // V: dim group (0..7)

  auto load_tile = [&](int K0){
    int keyr = (K0 + kkey < cb) ? (K0 + kkey) : 0;
    const unsigned short* kp = basep + (size_t)keyr*1536 + 512 + h*64 + kdo;
    kA = *(const uint4*)(kp);
    kB = *(const uint4*)(kp + 8);
    int k0g = K0 + 2*vkp2;
    int kr0 = (k0g   < cb) ? k0g   : 0;
    int kr1 = (k0g+1 < cb) ? k0g+1 : 0;
    vA = *(const uint4*)(basep + (size_t)kr0*1536 + 1024 + h*64 + vd8*8);
    vC = *(const uint4*)(basep + (size_t)kr1*1536 + 1024 + h*64 + vd8*8);
  };
  auto store_tile = [&](){
    int g0 = (t & 3) * 2;
    int gs0 = g0 ^ (kkey & 7), gs1 = (g0+1) ^ (kkey & 7);
    *(uint4*)(Ku + kkey*32 + gs0*4) = kA;
    *(uint4*)(Ku + kkey*32 + gs1*4) = kB;
    unsigned int au[4] = {vA.x, vA.y, vA.z, vA.w};
    unsigned int cu[4] = {vC.x, vC.y, vC.z, vC.w};
    int k8 = vkp2 >> 2;
    #pragma unroll
    for (int dd=0; dd<8; dd++){
      int d = vd8*8 + dd;
      Vu[d*32 + (k8 ^ (d&7))*4 + (vkp2 & 3)] =
          pk2(ext16(au[dd>>1], dd&1), ext16(cu[dd>>1], dd&1));
    }
  };

  const int nt = (cb + 63)/64;
  load_tile(0);
  for (int kt=0; kt<nt; kt++){
    int K0 = kt*64;
    __syncthreads();            // LDS consumers of previous tile done
    store_tile();               // regs -> LDS (swizzled)
    __syncthreads();            // LDS visible to all waves
    if (kt+1 < nt) load_tile((kt+1)*64);   // prefetch next tile during compute

    f32x4 acc[4];
    #pragma unroll
    for (int mt=0;mt<4;mt++) acc[mt] = (f32x4){0.f,0.f,0.f,0.f};
    #pragma unroll
    for (int mt=0;mt<4;mt++){
      int row = mt*16 + l15;
      #pragma unroll
      for (int c=0;c<2;c++){
        int gs = (c*4 + l4) ^ (row & 7);
        bf16x8 kf = *(const bf16x8*)&Kbf[row*64 + gs*8];
        acc[mt] = __builtin_amdgcn_mfma_f32_16x16x32_bf16(kf, Qf[c], acc[mt], 0,0,0);
      }
    }
    float p[4][4];
    float tmax = -1e30f;
    #pragma unroll
    for (int mt=0;mt<4;mt++)
      #pragma unroll
      for (int r=0;r<4;r++){
        int key = K0 + mt*16 + l4*4 + r;
        float s = (key < cb) ? acc[mt][r]*SCLOG2 : -1e30f;   // log2-domain score
        p[mt][r] = s;
        tmax = fmaxf(tmax, s);
      }
    tmax = fmaxf(tmax, __shfl_xor(tmax, 16));
    tmax = fmaxf(tmax, __shfl_xor(tmax, 32));
    float m_new = fmaxf(m_run, tmax);
    float alpha = fexp2(m_run - m_new);
    float psum = 0.f;
    #pragma unroll
    for (int mt=0;mt<4;mt++)
      #pragma unroll
      for (int r=0;r<4;r++){
        float pv = fexp2(p[mt][r] - m_new);
        p[mt][r] = pv; psum += pv;
      }
    psum += __shfl_xor(psum, 16);
    psum += __shfl_xor(psum, 32);
    l_run = l_run*alpha + psum;
    m_run = m_new;

    #pragma unroll
    for (int mt=0;mt<4;mt++){
      int keyl = mt*16 + l4*4;
      int gs = (keyl >> 3) ^ (l15 & 7);
      uint2 w2;
      w2.x = pk2(f2bf(p[mt][0]), f2bf(p[mt][1]));
      w2.y = pk2(f2bf(p[mt][2]), f2bf(p[mt][3]));
      *(uint2*)&Pbuf[w][ l15*64 + gs*8 + (keyl & 7) ] = w2;
    }
    #pragma unroll
    for (int mt=0;mt<4;mt++){
      accO[mt][0]*=alpha; accO[mt][1]*=alpha; accO[mt][2]*=alpha; accO[mt][3]*=alpha;
    }
    #pragma unroll
    for (int c2=0;c2<2;c2++){
      int gpv = (c2*4 + l4) ^ (l15 & 7);
      bf16x8 pf = *(const bf16x8*)&Pbuf[w][ l15*64 + gpv*8 ];
      #pragma unroll
      for (int mt=0;mt<4;mt++){
        int d = mt*16 + l15;
        int gv = (c2*4 + l4) ^ (d & 7);
        bf16x8 vf = *(const bf16x8*)&Vt[ d*64 + gv*8 ];
        accO[mt] = __builtin_amdgcn_mfma_f32_16x16x32_bf16(vf, pf, accO[mt], 0,0,0);
      }
    }
  }
  if (qg < cb){
    float inv = 1.f/l_run;
    size_t ro = ((size_t)(vb*S_TOT) + qg)*512 + h*64;
    #pragma unroll
    for (int mt=0;mt<4;mt++){
      float v0 = accO[mt][0]*inv, v1 = accO[mt][1]*inv;
      float v2 = accO[mt][2]*inv, v3 = accO[mt][3]*inv;
      unsigned short h0=f2bf(v0), h1=f2bf(v1), h2=f2bf(v2), h3=f2bf(v3);
      uint2 hw; hw.x = pk2(h0,h1); hw.y = pk2(h2,h3);
      uint2 lw;
      lw.x = pk2(f2bf(v0-bfval(h0)), f2bf(v1-bfval(h1)));
      lw.y = pk2(f2bf(v2-bfval(h2)), f2bf(v3-bfval(h3)));
      *(uint2*)&Oh[ro + mt*16 + l4*4] = hw;
      *(uint2*)&Ol[ro + mt*16 + l4*4] = lw;
    }
  }
}

// ---------------------------------------------------------------------------
// q0[vb][n] = bq[n] + dot(Wq_row_n, a1[vb,row0]); wave-per-neuron, fp32 exact.
// ---------------------------------------------------------------------------
__global__ __launch_bounds__(256) void row0_q_kernel(
    const unsigned short* __restrict__ Ah, const unsigned short* __restrict__ Al,
    const float* __restrict__ Wq, const float* __restrict__ bq,
    float* __restrict__ q0) {
  int vb = blockIdx.y;
  int n = blockIdx.x*4 + (threadIdx.x >> 6);
  int lane = threadIdx.x & 63;
  __shared__ float xs[512];
  size_t ro = (size_t)(vb*S_TOT)*512;
  for (int i=threadIdx.x; i<512; i+=256)
    xs[i] = bfval(Ah[ro+i]) + bfval(Al[ro+i]);
  __syncthreads();
  const float* wr = Wq + (size_t)n*512;
  float acc = 0.f;
  #pragma unroll
  for (int k=lane*4; k<512; k+=256){
    float4 u = *(const float4*)(wr + k);
    acc += xs[k]*u.x + xs[k+1]*u.y + xs[k+2]*u.z + xs[k+3]*u.w;
  }
  #pragma unroll
  for (int o=32;o;o>>=1) acc += __shfl_down(acc, o);
  if (lane==0) q0[vb*512 + n] = acc + bq[n];
}

// ---------------------------------------------------------------------------
// Split-K row-0 attention, phase 1 (log2-domain softmax): block (h, vb, chunk).
// partM stored in log2 domain.
// ---------------------------------------------------------------------------
__global__ __launch_bounds__(256) void attn_row0_part_kernel(
    const unsigned short* __restrict__ kv, const float* __restrict__ q0,
    const int* __restrict__ cnt,
    float* __restrict__ partM, float* __restrict__ partL,
    float* __restrict__ partN) {
  int h = blockIdx.x, vb = blockIdx.y, c = blockIdx.z;
  int cb = cnt[vb];
  int chunk = (cb + NCHUNK-1)/NCHUNK;
  int j0 = c*chunk;
  int j1 = j0+chunk; if (j1 > cb) j1 = cb;
  int t = threadIdx.x;
  int pidx = (vb*NH + h)*NCHUNK + c;
  __shared__ float qs[64];
  __shared__ float sc[144];     // chunk <= ceil(2049/16) = 129
  __shared__ float red[8];
  __shared__ float redO[4][64];
  if (t < 64) qs[t] = q0[vb*512 + h*64 + t]*SCLOG2;
  __syncthreads();
  if (j0 >= cb){
    if (t == 0){ partM[pidx] = -1e30f; partL[pidx] = 0.f; }
    if (t < 64) partN[(size_t)pidx*64 + t] = 0.f;
    return;
  }
  const unsigned short* base = kv + (size_t)vb*S_TOT*1024;
  int len = j1 - j0;
  float lmax = -1e30f;
  for (int jj=t; jj<len; jj+=256){
    const unsigned short* kp = base + (size_t)(j0+jj)*1024 + h*64;
    float s = 0.f;
    #pragma unroll
    for (int d8=0; d8<8; d8++){
      uint4 a = *(const uint4*)(kp + d8*8);
      unsigned int au[4] = {a.x,a.y,a.z,a.w};
      #pragma unroll
      for (int q2=0; q2<4; q2++){
        s += qs[d8*8+q2*2]*bfval(ext16(au[q2],0))
           + qs[d8*8+q2*2+1]*bfval(ext16(au[q2],1));
      }
    }
    sc[jj] = s;
    lmax = fmaxf(lmax, s);
  }
  #pragma unroll
  for (int o=32;o;o>>=1) lmax = fmaxf(lmax, __shfl_down(lmax,o));
  if ((t&63)==0) red[t>>6] = lmax;
  __syncthreads();
  float m = fmaxf(fmaxf(red[0],red[1]),fmaxf(red[2],red[3]));
  float lsum = 0.f;
  for (int jj=t; jj<len; jj+=256){
    float p = fexp2(sc[jj]-m);
    sc[jj] = p; lsum += p;
  }
  #pragma unroll
  for (int o=32;o;o>>=1) lsum += __shfl_down(lsum,o);
  __syncthreads();
  if ((t&63)==0) red[t>>6] = lsum;
  __syncthreads();
  float l = red[0]+red[1]+red[2]+red[3];
  int d = t & 63, rr = t >> 6;
  float acc = 0.f;
  for (int jj=rr; jj<len; jj+=4)
    acc += sc[jj]*bfval(base[(size_t)(j0+jj)*1024 + 512 + h*64 + d]);
  redO[rr][d] = acc;
  __syncthreads();
  if (t < 64){
    partN[(size_t)pidx*64 + t] = redO[0][t]+redO[1][t]+redO[2][t]+redO[3][t];
    if (t==0){ partM[pidx] = m; partL[pidx] = l; }
  }
}

// ---------------------------------------------------------------------------
// layer-1 out-proj for row 0: fused split-K combine (partM in log2 domain)
// + GEMV + residual(z row0) + LN -> cls embedding slot. grid = VB.
// ---------------------------------------------------------------------------
__global__ __launch_bounds__(256) void row0_proj_ln_kernel(
    const float* __restrict__ partM, const float* __restrict__ partL,
    const float* __restrict__ partN,
    const float* __restrict__ Wo, const float* __restrict__ bo,
    const unsigned short* __restrict__ Zh, const unsigned short* __restrict__ Zl,
    const float* __restrict__ g, const float* __restrict__ be,
    float* __restrict__ clsbuf) {
  int vb = blockIdx.x, t = threadIdx.x;
  int b = vb & 3, branch = vb >> 2;
  __shared__ float xin[512];
  __shared__ float y[512];
  __shared__ float red[16];
  {   // combine: thread t -> head t>>5, d = (t&31) and (t&31)+32
    int h = t >> 5, dl = t & 31;
    int pb = (vb*NH + h)*NCHUNK;
    float m = -1e30f;
    #pragma unroll
    for (int c=0;c<NCHUNK;c++) m = fmaxf(m, partM[pb+c]);
    float lsum=0.f, n0=0.f, n1=0.f;
    #pragma unroll
    for (int c=0;c<NCHUNK;c++){
      float w = fexp2(partM[pb+c]-m);
      lsum += w*partL[pb+c];
      n0   += w*partN[(size_t)(pb+c)*64 + dl];
      n1   += w*partN[(size_t)(pb+c)*64 + dl+32];
    }
    float inv = 1.f/lsum;
    xin[h*64 + dl]    = n0*inv;
    xin[h*64 + dl+32] = n1*inv;
  }
  __syncthreads();
  size_t z0 = (size_t)vb*S_TOT*512;
  for (int n=t;n<512;n+=256){
    const float4* wr = (const float4*)(Wo + (size_t)n*512);
    float acc = bo[n];
    for (int k4=0;k4<128;k4++){
      float4 u = wr[k4]; int k=k4*4;
      acc += xin[k+0]*u.x + xin[k+1]*u.y + xin[k+2]*u.z + xin[k+3]*u.w;
    }
    y[n] = acc + bfval(Zh[z0+n]) + bfval(Zl[z0+n]);
  }
  __syncthreads();
  float s1=0.f, s2=0.f;
  for (int i=t;i<512;i+=256){ float a=y[i]; s1+=a; s2+=a*a; }
  #pragma unroll
  for (int o=32;o;o>>=1){ s1+=__shfl_down(s1,o); s2+=__shfl_down(s2,o); }
  if ((t&63)==0){ red[t>>6]=s1; red[8+(t>>6)]=s2; }
  __syncthreads();
  s1 = red[0]+red[1]+red[2]+red[3];
  s2 = red[8]+red[9]+red[10]+red[11];
  float mean = s1*(1.f/512.f);
  float var  = s2*(1.f/512.f) - mean*mean;
  float rn = rsqrtf(var + 1e-5f);
  for (int i=t;i<512;i+=256)
    clsbuf[b*1024 + branch*512 + i] = (y[i]-mean)*rn*g[i] + be[i];
}

// ---------------------------------------------------------------------------
// Final MLP layer (wave-per-neuron GEMV).
// ---------------------------------------------------------------------------
__global__ __launch_bounds__(256) void fm_layer_kernel(
    const float* __restrict__ in, const float* __restrict__ W,
    const float* __restrict__ bias, float* __restrict__ out,
    int K, int N, int act) {
  int b = blockIdx.y;
  int n = blockIdx.x*4 + (threadIdx.x >> 6);
  int lane = threadIdx.x & 63;
  __shared__ float xs[1024];
  for (int i=threadIdx.x; i<K; i+=256) xs[i] = in[(size_t)b*K + i];
  __syncthreads();
  const float* wr = W + (size_t)n*K;
  float acc = 0.f;
  #pragma unroll 4
  for (int k=lane*4; k<K; k+=256){
    float4 u = *(const float4*)(wr + k);
    acc += xs[k]*u.x + xs[k+1]*u.y + xs[k+2]*u.z + xs[k+3]*u.w;
  }
  #pragma unroll
  for (int o=32;o;o>>=1) acc += __shfl_down(acc, o);
  if (lane==0){
    float v = acc + bias[n];
    if (act) v = gelu_exact(v);
    out[(size_t)b*N + n] = v;
  }
}

// ---------------------------------------------------------------------------
extern "C" void kernel_launch(void* const* d_in, const int* in_sizes, int n_in,
                              void* d_out, int out_size, void* d_ws, size_t ws_size,
                              hipStream_t stream) {
  const float* x      = (const float*)d_in[0];
  const float* cls_tk = (const float*)d_in[1];
  const float* ln_g   = (const float*)d_in[2];
  const float* ln_b   = (const float*)d_in[3];
  const float* aw_W0  = (const float*)d_in[4];  const float* aw_b0 = (const float*)d_in[5];
  const float* aw_W1  = (const float*)d_in[6];  const float* aw_b1 = (const float*)d_in[7];
  const float* aw_W2  = (const float*)d_in[8];  const float* aw_b2 = (const float*)d_in[9];
  const float* pr_W0  = (const float*)d_in[10]; const float* pr_b0 = (const float*)d_in[11];
  const float* pr_W1  = (const float*)d_in[12]; const float* pr_b1 = (const float*)d_in[13];
  const float* pr_W2  = (const float*)d_in[14]; const float* pr_b2 = (const float*)d_in[15];
  const float* mWqkv[2] = {(const float*)d_in[16], (const float*)d_in[20]};
  const float* mbqkv[2] = {(const float*)d_in[17], (const float*)d_in[21]};
  const float* mWo[2]   = {(const float*)d_in[18], (const float*)d_in[22]};
  const float* mbo[2]   = {(const float*)d_in[19], (const float*)d_in[23]};

  float* ws = (float*)d_ws;
  size_t off = 0;
  float* weight = ws + off; off += 8192;                      // [B,N]
  int*   idx    = (int*)(ws + off); off += VROWS + 8;         // [VB,S]
  int*   cnt    = (int*)(ws + off); off += 16;                // [VB]
  float* W0T    = ws + off; off += 32768;                     // [512][64]
  const size_t HBUF = (size_t)VROWS*512/2;                    // bf16 array in float units
  unsigned short* Zh = (unsigned short*)(ws + off); off += HBUF;
  unsigned short* Zl = (unsigned short*)(ws + off); off += HBUF;
  float* QKVr   = ws + off; off += (size_t)VROWS*1536/2;      // shared region (bf16-sized):
  unsigned short* QKVb = (unsigned short*)QKVr;               //  layer-0 QKV bf16 (stride 1536)
  float* T2     = QKVr;                                       //  out-proj fp32 (stride 512)
  unsigned short* KVb  = (unsigned short*)QKVr;               //  layer-1 KV bf16 (stride 1024)
  unsigned short* Oh = (unsigned short*)(ws + off); off += HBUF;  // also a1 hi
  unsigned short* Ol = (unsigned short*)(ws + off); off += HBUF;  // also a1 lo
  unsigned short* Wq0h = (unsigned short*)(ws + off); off += 393216;
  unsigned short* Wq0l = (unsigned short*)(ws + off); off += 393216;
  unsigned short* Wq1h = (unsigned short*)(ws + off); off += 393216;
  unsigned short* Wq1l = (unsigned short*)(ws + off); off += 393216;
  unsigned short* Wo0h = (unsigned short*)(ws + off); off += 131072;
  unsigned short* Wo0l = (unsigned short*)(ws + off); off += 131072;
  float* q0buf  = ws + off; off += VB*512;                    // [VB,D]
  float* clsb   = ws + off; off += 4096;                      // [B,2D]
  float* h1buf  = ws + off; off += 2048;                      // [B,D]
  float* h2buf  = ws + off; off += 2048;                      // [B,D]
  float* partM  = ws + off; off += VB*NH*NCHUNK;              // 1024
  float* partL  = ws + off; off += VB*NH*NCHUNK;              // 1024
  float* partN  = ws + off; off += (size_t)VB*NH*NCHUNK*64;   // 65536
  (void)ws_size; (void)in_sizes; (void)n_in; (void)out_size;

  transpose_w0_kernel<<<(32768+255)/256, 256, 0, stream>>>(aw_W0, W0T);
  aw_weight_kernel<<<B_SZ*N_INST, 64, 0, stream>>>(
      x, W0T, aw_b0, aw_W1, aw_b1, aw_W2, aw_b2, weight);

  split_kernel<<<(786432+255)/256, 256, 0, stream>>>(mWqkv[0], Wq0h, Wq0l, 786432);
  split_kernel<<<(786432+255)/256, 256, 0, stream>>>(mWqkv[1], Wq1h, Wq1l, 786432);
  split_kernel<<<(262144+255)/256, 256, 0, stream>>>(mWo[0],  Wo0h, Wo0l, 262144);

  const int MT = (VROWS + 63)/64;   // 257 row tiles
  // both branches batched as vb = branch*4 + b
  compact_kernel<<<VB, 256, 0, stream>>>(weight, idx, cnt);
  build_z_kernel<<<VROWS, 256, 0, stream>>>(x, weight, cls_tk, ln_g, ln_b, idx, cnt, Zh, Zl);
  // layer 0
  mfma_gemm_kernel<<<dim3(1536/64, MT), 256, 0, stream>>>(
      Zh, Zl, Wq0h, Wq0l, mbqkv[0], QKVb, VROWS, 1536, cnt, 1);
  flash_attn_kernel<<<dim3((S_TOT+63)/64, NH, VB), 256, 0, stream>>>(QKVb, cnt, Oh, Ol);
  mfma_gemm_kernel<<<dim3(512/64, MT), 256, 0, stream>>>(
      Oh, Ol, Wo0h, Wo0l, mbo[0], T2, VROWS, 512, cnt, 0);
  add_ln_kernel<<<VROWS, 256, 0, stream>>>(Zh, Zl, T2, ln_g, ln_b, cnt, Oh, Ol); // a1 -> Oh/Ol
  // layer 1: row0 Q via fp32 GEMV; KV for all rows, bf16 (stride 1024)
  row0_q_kernel<<<dim3(128, VB), 256, 0, stream>>>(Oh, Ol, mWqkv[1], mbqkv[1], q0buf);
  mfma_gemm_kernel<<<dim3(1024/64, MT), 256, 0, stream>>>(
      Oh, Ol, Wq1h + (size_t)512*512, Wq1l + (size_t)512*512,
      mbqkv[1] + 512, KVb, VROWS, 1024, cnt, 1);
  attn_row0_part_kernel<<<dim3(NH, VB, NCHUNK), 256, 0, stream>>>(
      KVb, q0buf, cnt, partM, partL, partN);
  row0_proj_ln_kernel<<<VB, 256, 0, stream>>>(
      partM, partL, partN, mWo[1], mbo[1], Zh, Zl, ln_g, ln_b, clsb);
  // final MLP: 3 wave-per-neuron GEMV layers
  fm_layer_kernel<<<dim3(128, B_SZ), 256, 0, stream>>>(clsb,  pr_W0, pr_b0, h1buf, 1024, 512, 1);
  fm_layer_kernel<<<dim3(128, B_SZ), 256, 0, stream>>>(h1buf, pr_W1, pr_b1, h2buf,  512, 512, 1);
  fm_layer_kernel<<<dim3(128, B_SZ), 256, 0, stream>>>(h2buf, pr_W2, pr_b2, (float*)d_out, 512, 512, 0);
}

// Round 16
// 454.485 us; speedup vs baseline: 1.0582x; 1.0582x over previous
//
#include <hip/hip_runtime.h>
#include <hip/hip_bf16.h>

#define B_SZ 4
#define N_INST 2048
#define D_MODEL 512
#define S_TOT 2049          // N+1 (cls prepended)
#define NH 8
#define HD 64
#define VB 8                // virtual batches = 2 branches x 4 batch
#define VROWS (VB*S_TOT)    // 16392
#define NCHUNK 16           // split-K chunks for row-0 attention
#define SCLOG2 0.18033688011112042f   // 0.125 * log2(e) — log2-domain score scale
#define FIXM 16.0f          // fixed softmax shift (log2 domain); |s_log2|<<16 always

typedef __attribute__((ext_vector_type(4))) float f32x4;
typedef __attribute__((ext_vector_type(8))) short bf16x8;

__device__ __forceinline__ float gelu_exact(float x){ return 0.5f*x*(1.f+erff(x*0.70710678118654752f)); }
__device__ __forceinline__ float fexp2(float x){ return __builtin_amdgcn_exp2f(x); } // raw v_exp_f32
__device__ __forceinline__ unsigned short f2bf(float x){
  unsigned int u = __float_as_uint(x);
  u += 0x7fffu + ((u>>16)&1u);
  return (unsigned short)(u>>16);
}
__device__ __forceinline__ float bfval(unsigned short u){ return __uint_as_float(((unsigned int)u)<<16); }
__device__ __forceinline__ unsigned int pk2(unsigned short lo, unsigned short hi){
  return (unsigned int)lo | ((unsigned int)hi << 16);
}
__device__ __forceinline__ unsigned short ext16(unsigned int u, int hi){
  return (unsigned short)(hi ? (u>>16) : (u & 0xffffu));
}

#define GLOAD16(gp, lp) __builtin_amdgcn_global_load_lds( \
    (const __attribute__((address_space(1))) void*)(gp), \
    (__attribute__((address_space(3))) void*)(lp), 16, 0, 0)

// ---------------------------------------------------------------------------
// One-time transpose: W0T[k][h] = W0[h][k]   (64x512 -> 512x64, fp32)
// ---------------------------------------------------------------------------
__global__ __launch_bounds__(256) void transpose_w0_kernel(
    const float* __restrict__ W0, float* __restrict__ W0T) {
  int i = blockIdx.x*256 + threadIdx.x;
  if (i < 64*512){
    int h = i >> 9, k = i & 511;
    W0T[k*64 + h] = W0[i];
  }
}

// ---------------------------------------------------------------------------
// Gating MLP (fp32: the w<0.5 mask is a threshold — bf16 risks branch flips).
// ---------------------------------------------------------------------------
__global__ __launch_bounds__(64) void aw_weight_kernel(
    const float* __restrict__ x,
    const float* __restrict__ W0T, const float* __restrict__ b0,
    const float* __restrict__ W1, const float* __restrict__ b1,
    const float* __restrict__ W2, const float* __restrict__ b2,
    float* __restrict__ weight) {
  int inst = blockIdx.x;
  int h = threadIdx.x;
  __shared__ float xs[512];
  __shared__ float hs[64];
  const float* xp = x + (size_t)inst*D_MODEL;
  for (int i=h;i<512;i+=64) xs[i] = xp[i];
  __syncthreads();
  float acc = b0[h];
  const float* w0c = W0T + h;
  #pragma unroll 16
  for (int k=0;k<512;k++)
    acc = fmaf(xs[k], w0c[k*64], acc);
  hs[h] = gelu_exact(acc);
  __syncthreads();
  const float4* w1 = (const float4*)(W1 + (size_t)h*64);
  float acc2 = b1[h];
  #pragma unroll
  for (int k4=0;k4<16;k4++){
    float4 u = w1[k4]; int k = k4*4;
    acc2 += hs[k+0]*u.x + hs[k+1]*u.y + hs[k+2]*u.z + hs[k+3]*u.w;
  }
  float h2 = gelu_exact(acc2);
  float p = h2 * W2[h];
  #pragma unroll
  for (int o=32;o;o>>=1) p += __shfl_down(p, o);
  if (h==0){
    float s = p + b2[0];
    weight[inst] = 1.f/(1.f+expf(-s));
  }
}

// ---------------------------------------------------------------------------
// Split fp32 -> (hi, lo) bf16 pair.
// ---------------------------------------------------------------------------
__global__ __launch_bounds__(256) void split_kernel(
    const float* __restrict__ w, unsigned short* __restrict__ hi,
    unsigned short* __restrict__ lo, int n) {
  int i = blockIdx.x*256 + threadIdx.x;
  if (i < n){
    float v = w[i];
    unsigned short h = f2bf(v);
    hi[i] = h;
    lo[i] = f2bf(v - bfval(h));
  }
}

// ---------------------------------------------------------------------------
// Compaction per virtual batch vb = branch*4 + b (slot0 = cls).
// ---------------------------------------------------------------------------
__global__ __launch_bounds__(256) void compact_kernel(
    const float* __restrict__ weight,
    int* __restrict__ idx, int* __restrict__ cnt) {
  int vb = blockIdx.x;
  int b = vb & 3, branch = vb >> 2;
  int t = threadIdx.x;
  int lane = t & 63, wv = t >> 6;
  __shared__ int wsum[4];
  __shared__ int base_s;
  if (t==0){ idx[vb*S_TOT] = 0; base_s = 1; }
  __syncthreads();
  for (int c0=0; c0<N_INST; c0+=256){
    int n = c0 + t;
    float w = weight[b*N_INST + n];
    bool neg = (w < 0.5f);
    bool val = (branch==0) ? neg : !neg;
    unsigned long long m = __ballot(val);
    int prefix = __popcll(m & ((1ull<<lane)-1ull));
    if (lane==0) wsum[wv] = __popcll(m);
    __syncthreads();
    int wbase = 0;
    #pragma unroll
    for (int i=0;i<4;i++) if (i<wv) wbase += wsum[i];
    int total = wsum[0]+wsum[1]+wsum[2]+wsum[3];
    int mybase = base_s;
    if (val) idx[vb*S_TOT + mybase + wbase + prefix] = n + 1;
    __syncthreads();
    if (t==0) base_s += total;
    __syncthreads();
  }
  if (t==0) cnt[vb] = base_s;
}

// ---------------------------------------------------------------------------
// Build compacted z = LN(scale*seq[idx]) -> hi/lo bf16 pair. grid = VROWS.
// ---------------------------------------------------------------------------
__global__ __launch_bounds__(256) void build_z_kernel(
    const float* __restrict__ x, const float* __restrict__ weight,
    const float* __restrict__ cls, const float* __restrict__ g, const float* __restrict__ be,
    const int* __restrict__ idx, const int* __restrict__ cnt,
    unsigned short* __restrict__ Zh, unsigned short* __restrict__ Zl) {
  int row = blockIdx.x;
  int vb = row / S_TOT, slot = row % S_TOT;
  if (slot >= cnt[vb]) return;
  int b = vb & 3, branch = vb >> 2;
  int t = threadIdx.x;
  __shared__ float v[512];
  __shared__ float red[16];
  int pos = idx[vb*S_TOT + slot];
  float scale = 1.f;
  const float* src = cls;
  if (pos != 0){
    float w = weight[b*N_INST + (pos-1)];
    scale = (branch==0) ? powf(w, 1.5f) : powf(w, 2.0f/3.0f);
    src = x + ((size_t)b*N_INST + (pos-1))*D_MODEL;
  }
  float s1=0.f, s2=0.f;
  for (int i=t;i<512;i+=256){
    float val = src[i];
    if (pos != 0) val *= scale;
    v[i]=val; s1+=val; s2+=val*val;
  }
  __syncthreads();
  #pragma unroll
  for (int o=32;o;o>>=1){ s1+=__shfl_down(s1,o); s2+=__shfl_down(s2,o); }
  if ((t&63)==0){ red[t>>6]=s1; red[8+(t>>6)]=s2; }
  __syncthreads();
  s1 = red[0]+red[1]+red[2]+red[3];
  s2 = red[8]+red[9]+red[10]+red[11];
  float mean = s1 * (1.f/512.f);
  float var  = s2 * (1.f/512.f) - mean*mean;
  float rn = rsqrtf(var + 1e-5f);
  size_t ro = (size_t)row*512;
  for (int i=t;i<512;i+=256){
    float o = (v[i]-mean)*rn*g[i] + be[i];
    unsigned short hbits = f2bf(o);
    Zh[ro+i] = hbits;
    Zl[ro+i] = f2bf(o - bfval(hbits));
  }
}

// out = LN((Zh+Zl) + T2) rowwise -> hi/lo bf16 pair (the a1 operand)
__global__ __launch_bounds__(256) void add_ln_kernel(
    const unsigned short* __restrict__ Zh, const unsigned short* __restrict__ Zl,
    const float* __restrict__ T2,
    const float* __restrict__ g, const float* __restrict__ be,
    const int* __restrict__ cnt,
    unsigned short* __restrict__ Ah, unsigned short* __restrict__ Al) {
  int row = blockIdx.x;
  if ((row % S_TOT) >= cnt[row / S_TOT]) return;
  int t = threadIdx.x;
  __shared__ float v[512];
  __shared__ float red[16];
  size_t ro = (size_t)row*512;
  float s1=0.f, s2=0.f;
  for (int i=t;i<512;i+=256){
    float val = bfval(Zh[ro+i]) + bfval(Zl[ro+i]) + T2[ro+i];
    v[i]=val; s1+=val; s2+=val*val;
  }
  __syncthreads();
  #pragma unroll
  for (int o=32;o;o>>=1){ s1+=__shfl_down(s1,o); s2+=__shfl_down(s2,o); }
  if ((t&63)==0){ red[t>>6]=s1; red[8+(t>>6)]=s2; }
  __syncthreads();
  s1 = red[0]+red[1]+red[2]+red[3];
  s2 = red[8]+red[9]+red[10]+red[11];
  float mean = s1 * (1.f/512.f);
  float var  = s2 * (1.f/512.f) - mean*mean;
  float rn = rsqrtf(var + 1e-5f);
  for (int i=t;i<512;i+=256){
    float o = (v[i]-mean)*rn*g[i] + be[i];
    unsigned short hbits = f2bf(o);
    Ah[ro+i] = hbits;
    Al[ro+i] = f2bf(o - bfval(hbits));
  }
}

// ---------------------------------------------------------------------------
// MFMA GEMM (bf16 hi/lo 3-pass): C[M,N] = (Ah+Al)[M,512] @ (Wh+Wl)[N,512]^T + bias.
// obf16=1 -> write bf16 (ushort, stride N); else fp32.
// ---------------------------------------------------------------------------
__global__ __launch_bounds__(256) void mfma_gemm_kernel(
    const unsigned short* __restrict__ Ahg, const unsigned short* __restrict__ Alg,
    const unsigned short* __restrict__ Whg, const unsigned short* __restrict__ Wlg,
    const float* __restrict__ bias, void* __restrict__ Cout,
    int M, int N, const int* __restrict__ cnt, int obf16) {
  int t = threadIdx.x;
  int bm = blockIdx.y*64, bn = blockIdx.x*64;
  {
    int r = bm + (t>>2);
    bool ok = (r < M) && ((r % S_TOT) < cnt[r / S_TOT]);
    if (__syncthreads_or(ok ? 1 : 0) == 0) return;
  }
  __shared__ unsigned short Ahs[64*64], Als[64*64], Whs[64*64], Wls[64*64];
  int lane = t & 63, w = t >> 6;
  int l15 = lane & 15, l4 = lane >> 4;

  const unsigned short* src;
  unsigned short* dst;
  if      (w == 0){ src = Ahg; dst = Ahs; }
  else if (w == 1){ src = Alg; dst = Als; }
  else if (w == 2){ src = Whg; dst = Whs; }
  else            { src = Wlg; dst = Wls; }
  int tb  = (w < 2) ? bm : bn;
  int lim = (w < 2) ? M  : N;
  int lrow = lane >> 3;
  int lg   = lane & 7;
  const unsigned short* gp[8];
  #pragma unroll
  for (int i=0;i<8;i++){
    int row_l = i*8 + lrow;
    int rg = tb + row_l; if (rg >= lim) rg = lim-1;
    gp[i] = src + (size_t)rg*512 + (size_t)((lg ^ (row_l&7))*8);
  }

  f32x4 acc[4];
  #pragma unroll
  for (int mt=0;mt<4;mt++) acc[mt] = (f32x4){0.f,0.f,0.f,0.f};

  for (int ch=0; ch<8; ch++){
    __syncthreads();
    #pragma unroll
    for (int i=0;i<8;i++)
      GLOAD16(gp[i] + ch*64, dst + i*512);
    __syncthreads();
    #pragma unroll
    for (int ks=0; ks<2; ks++){
      int wrow = w*16 + l15;
      int wgs = (ks*4 + l4) ^ (wrow & 7);
      bf16x8 wh = *(const bf16x8*)&Whs[wrow*64 + wgs*8];
      bf16x8 wl = *(const bf16x8*)&Wls[wrow*64 + wgs*8];
      #pragma unroll
      for (int mt=0;mt<4;mt++){
        int arow = mt*16 + l15;
        int ags = (ks*4 + l4) ^ (arow & 7);
        bf16x8 ah = *(const bf16x8*)&Ahs[arow*64 + ags*8];
        bf16x8 al = *(const bf16x8*)&Als[arow*64 + ags*8];
        acc[mt] = __builtin_amdgcn_mfma_f32_16x16x32_bf16(ah, wh, acc[mt], 0,0,0);
        acc[mt] = __builtin_amdgcn_mfma_f32_16x16x32_bf16(ah, wl, acc[mt], 0,0,0);
        acc[mt] = __builtin_amdgcn_mfma_f32_16x16x32_bf16(al, wh, acc[mt], 0,0,0);
      }
    }
  }
  int ncol = bn + w*16 + l15;
  float bv = bias[ncol];
  #pragma unroll
  for (int mt=0;mt<4;mt++){
    #pragma unroll
    for (int r=0;r<4;r++){
      int mrow = bm + mt*16 + l4*4 + r;
      bool ok = (mrow < M) && ((mrow % S_TOT) < cnt[mrow / S_TOT]);
      if (ok){
        float v = acc[mt][r] + bv;
        if (obf16) ((unsigned short*)Cout)[(size_t)mrow*N + ncol] = f2bf(v);
        else       ((float*)Cout)[(size_t)mrow*N + ncol] = v;
      }
    }
  }
}

// ---------------------------------------------------------------------------
// MFMA flash attention (layer 0), bf16 QKV (stride 1536), vb = blockIdx.z.
// 64-query tile. Fixed-shift softmax (shift-invariance): p = exp2(s - FIXM)
// with raw v_exp_f32 — no running max, no rescaling, l reduced once at end.
// ---------------------------------------------------------------------------
__global__ __launch_bounds__(256) void flash_attn_kernel(
    const unsigned short* __restrict__ qkv, const int* __restrict__ cnt,
    unsigned short* __restrict__ Oh, unsigned short* __restrict__ Ol) {
  int vb = blockIdx.z, h = blockIdx.y;
  int cb = cnt[vb];
  int S0 = blockIdx.x * 64;
  if (S0 >= cb) return;
  int t = threadIdx.x;
  int lane = t & 63, w = t >> 6;
  int l15 = lane & 15, l4 = lane >> 4;

  __shared__ unsigned short Kbf[64*64];
  __shared__ unsigned short Vt[64*64];
  __shared__ unsigned short Pbuf[4][16*64];

  const unsigned short* basep = qkv + (size_t)(vb*S_TOT)*1536;

  int qg = S0 + w*16 + l15;
  int qr = (qg < cb) ? qg : 0;
  const unsigned short* qp = basep + (size_t)qr*1536 + h*64;
  bf16x8 Qf[2];
  Qf[0] = *(const bf16x8*)(qp + l4*8);
  Qf[1] = *(const bf16x8*)(qp + 32 + l4*8);

  float l_run = 0.f;                // per-lane partial; reduced in epilogue
  f32x4 accO[4];
  #pragma unroll
  for (int mt=0;mt<4;mt++) accO[mt] = (f32x4){0.f,0.f,0.f,0.f};

  unsigned int* Ku = (unsigned int*)Kbf;
  unsigned int* Vu = (unsigned int*)Vt;
  const int nt = (cb + 63)/64;
  for (int kt=0; kt<nt; kt++){
    int K0 = kt*64;
    __syncthreads();
    {   // stage K rows -> Kbf[key][d]
      int key = t>>2;
      int keyr = (K0+key < cb) ? (K0+key) : 0;
      const unsigned short* kp = basep + (size_t)keyr*1536 + 512 + h*64 + (t&3)*16;
      uint4 a  = *(const uint4*)(kp);
      uint4 b2 = *(const uint4*)(kp+8);
      int g0 = (t&3)*2;
      int gs0 = g0 ^ (key&7), gs1 = (g0+1) ^ (key&7);
      *(uint4*)(Ku + key*32 + gs0*4) = a;
      *(uint4*)(Ku + key*32 + gs1*4) = b2;
    }
    {   // stage V transposed -> Vt[d][key]
      int kp2 = t & 31;
      int d8 = t >> 5;
      int k0g = K0 + 2*kp2;
      int kr0 = (k0g   < cb) ? k0g   : 0;
      int kr1 = (k0g+1 < cb) ? k0g+1 : 0;
      const unsigned short* vp0 = basep + (size_t)kr0*1536 + 1024 + h*64 + d8*8;
      const unsigned short* vp1 = basep + (size_t)kr1*1536 + 1024 + h*64 + d8*8;
      uint4 a = *(const uint4*)(vp0);
      uint4 c = *(const uint4*)(vp1);
      unsigned int au[4] = {a.x,a.y,a.z,a.w};
      unsigned int cu[4] = {c.x,c.y,c.z,c.w};
      int k8 = kp2 >> 2;
      #pragma unroll
      for (int dd=0; dd<8; dd++){
        int d = d8*8 + dd;
        Vu[d*32 + (k8 ^ (d&7))*4 + (kp2&3)] =
            pk2(ext16(au[dd>>1], dd&1), ext16(cu[dd>>1], dd&1));
      }
    }
    __syncthreads();

    f32x4 acc[4];
    #pragma unroll
    for (int mt=0;mt<4;mt++) acc[mt] = (f32x4){0.f,0.f,0.f,0.f};
    #pragma unroll
    for (int mt=0;mt<4;mt++){
      int row = mt*16 + l15;
      #pragma unroll
      for (int c=0;c<2;c++){
        int gs = (c*4 + l4) ^ (row & 7);
        bf16x8 kf = *(const bf16x8*)&Kbf[row*64 + gs*8];
        acc[mt] = __builtin_amdgcn_mfma_f32_16x16x32_bf16(kf, Qf[c], acc[mt], 0,0,0);
      }
    }
    // fixed-shift softmax: p = exp2(s*SCLOG2 - FIXM); no max, no rescale
    float p[4][4];
    #pragma unroll
    for (int mt=0;mt<4;mt++)
      #pragma unroll
      for (int r=0;r<4;r++){
        int key = K0 + mt*16 + l4*4 + r;
        float pv = (key < cb) ? fexp2(fmaf(acc[mt][r], SCLOG2, -FIXM)) : 0.f;
        p[mt][r] = pv;
        l_run += pv;
      }

    #pragma unroll
    for (int mt=0;mt<4;mt++){
      int keyl = mt*16 + l4*4;
      int gs = (keyl >> 3) ^ (l15 & 7);
      uint2 w2;
      w2.x = pk2(f2bf(p[mt][0]), f2bf(p[mt][1]));
      w2.y = pk2(f2bf(p[mt][2]), f2bf(p[mt][3]));
      *(uint2*)&Pbuf[w][ l15*64 + gs*8 + (keyl & 7) ] = w2;
    }
    #pragma unroll
    for (int c2=0;c2<2;c2++){
      int gpv = (c2*4 + l4) ^ (l15 & 7);
      bf16x8 pf = *(const bf16x8*)&Pbuf[w][ l15*64 + gpv*8 ];
      #pragma unroll
      for (int mt=0;mt<4;mt++){
        int d = mt*16 + l15;
        int gv = (c2*4 + l4) ^ (d & 7);
        bf16x8 vf = *(const bf16x8*)&Vt[ d*64 + gv*8 ];
        accO[mt] = __builtin_amdgcn_mfma_f32_16x16x32_bf16(vf, pf, accO[mt], 0,0,0);
      }
    }
  }
  // reduce l across the 4 key-groups (lanes sharing l15)
  l_run += __shfl_xor(l_run, 16);
  l_run += __shfl_xor(l_run, 32);
  if (qg < cb){
    float inv = 1.f/l_run;
    size_t ro = ((size_t)(vb*S_TOT) + qg)*512 + h*64;
    #pragma unroll
    for (int mt=0;mt<4;mt++){
      float v0 = accO[mt][0]*inv, v1 = accO[mt][1]*inv;
      float v2 = accO[mt][2]*inv, v3 = accO[mt][3]*inv;
      unsigned short h0=f2bf(v0), h1=f2bf(v1), h2=f2bf(v2), h3=f2bf(v3);
      uint2 hw; hw.x = pk2(h0,h1); hw.y = pk2(h2,h3);
      uint2 lw;
      lw.x = pk2(f2bf(v0-bfval(h0)), f2bf(v1-bfval(h1)));
      lw.y = pk2(f2bf(v2-bfval(h2)), f2bf(v3-bfval(h3)));
      *(uint2*)&Oh[ro + mt*16 + l4*4] = hw;
      *(uint2*)&Ol[ro + mt*16 + l4*4] = lw;
    }
  }
}

// ---------------------------------------------------------------------------
// q0[vb][n] = bq[n] + dot(Wq_row_n, a1[vb,row0]); wave-per-neuron, fp32 exact.
// ---------------------------------------------------------------------------
__global__ __launch_bounds__(256) void row0_q_kernel(
    const unsigned short* __restrict__ Ah, const unsigned short* __restrict__ Al,
    const float* __restrict__ Wq, const float* __restrict__ bq,
    float* __restrict__ q0) {
  int vb = blockIdx.y;
  int n = blockIdx.x*4 + (threadIdx.x >> 6);
  int lane = threadIdx.x & 63;
  __shared__ float xs[512];
  size_t ro = (size_t)(vb*S_TOT)*512;
  for (int i=threadIdx.x; i<512; i+=256)
    xs[i] = bfval(Ah[ro+i]) + bfval(Al[ro+i]);
  __syncthreads();
  const float* wr = Wq + (size_t)n*512;
  float acc = 0.f;
  #pragma unroll
  for (int k=lane*4; k<512; k+=256){
    float4 u = *(const float4*)(wr + k);
    acc += xs[k]*u.x + xs[k+1]*u.y + xs[k+2]*u.z + xs[k+3]*u.w;
  }
  #pragma unroll
  for (int o=32;o;o>>=1) acc += __shfl_down(acc, o);
  if (lane==0) q0[vb*512 + n] = acc + bq[n];
}

// ---------------------------------------------------------------------------
// Split-K row-0 attention, phase 1 (fixed-shift softmax, single pass):
// block (h, vb, chunk). partM = FIXM for nonempty chunks.
// ---------------------------------------------------------------------------
__global__ __launch_bounds__(256) void attn_row0_part_kernel(
    const unsigned short* __restrict__ kv, const float* __restrict__ q0,
    const int* __restrict__ cnt,
    float* __restrict__ partM, float* __restrict__ partL,
    float* __restrict__ partN) {
  int h = blockIdx.x, vb = blockIdx.y, c = blockIdx.z;
  int cb = cnt[vb];
  int chunk = (cb + NCHUNK-1)/NCHUNK;
  int j0 = c*chunk;
  int j1 = j0+chunk; if (j1 > cb) j1 = cb;
  int t = threadIdx.x;
  int pidx = (vb*NH + h)*NCHUNK + c;
  __shared__ float qs[64];
  __shared__ float sc[144];     // chunk <= ceil(2049/16) = 129
  __shared__ float red[8];
  __shared__ float redO[4][64];
  if (t < 64) qs[t] = q0[vb*512 + h*64 + t]*SCLOG2;
  __syncthreads();
  if (j0 >= cb){
    if (t == 0){ partM[pidx] = -1e30f; partL[pidx] = 0.f; }
    if (t < 64) partN[(size_t)pidx*64 + t] = 0.f;
    return;
  }
  const unsigned short* base = kv + (size_t)vb*S_TOT*1024;
  int len = j1 - j0;
  float lsum = 0.f;
  for (int jj=t; jj<len; jj+=256){
    const unsigned short* kp = base + (size_t)(j0+jj)*1024 + h*64;
    float s = 0.f;
    #pragma unroll
    for (int d8=0; d8<8; d8++){
      uint4 a = *(const uint4*)(kp + d8*8);
      unsigned int au[4] = {a.x,a.y,a.z,a.w};
      #pragma unroll
      for (int q2=0; q2<4; q2++){
        s += qs[d8*8+q2*2]*bfval(ext16(au[q2],0))
           + qs[d8*8+q2*2+1]*bfval(ext16(au[q2],1));
      }
    }
    float p = fexp2(s - FIXM);
    sc[jj] = p;
    lsum += p;
  }
  #pragma unroll
  for (int o=32;o;o>>=1) lsum += __shfl_down(lsum,o);
  if ((t&63)==0) red[t>>6] = lsum;
  __syncthreads();
  float l = red[0]+red[1]+red[2]+red[3];
  int d = t & 63, rr = t >> 6;
  float acc = 0.f;
  for (int jj=rr; jj<len; jj+=4)
    acc += sc[jj]*bfval(base[(size_t)(j0+jj)*1024 + 512 + h*64 + d]);
  redO[rr][d] = acc;
  __syncthreads();
  if (t < 64){
    partN[(size_t)pidx*64 + t] = redO[0][t]+redO[1][t]+redO[2][t]+redO[3][t];
    if (t==0){ partM[pidx] = FIXM; partL[pidx] = l; }
  }
}

// ---------------------------------------------------------------------------
// layer-1 out-proj for row 0: fused split-K combine (partM in log2 domain)
// + GEMV + residual(z row0) + LN -> cls embedding slot. grid = VB.
// ---------------------------------------------------------------------------
__global__ __launch_bounds__(256) void row0_proj_ln_kernel(
    const float* __restrict__ partM, const float* __restrict__ partL,
    const float* __restrict__ partN,
    const float* __restrict__ Wo, const float* __restrict__ bo,
    const unsigned short* __restrict__ Zh, const unsigned short* __restrict__ Zl,
    const float* __restrict__ g, const float* __restrict__ be,
    float* __restrict__ clsbuf) {
  int vb = blockIdx.x, t = threadIdx.x;
  int b = vb & 3, branch = vb >> 2;
  __shared__ float xin[512];
  __shared__ float y[512];
  __shared__ float red[16];
  {   // combine: thread t -> head t>>5, d = (t&31) and (t&31)+32
    int h = t >> 5, dl = t & 31;
    int pb = (vb*NH + h)*NCHUNK;
    float m = -1e30f;
    #pragma unroll
    for (int c=0;c<NCHUNK;c++) m = fmaxf(m, partM[pb+c]);
    float lsum=0.f, n0=0.f, n1=0.f;
    #pragma unroll
    for (int c=0;c<NCHUNK;c++){
      float w = fexp2(partM[pb+c]-m);
      lsum += w*partL[pb+c];
      n0   += w*partN[(size_t)(pb+c)*64 + dl];
      n1   += w*partN[(size_t)(pb+c)*64 + dl+32];
    }
    float inv = 1.f/lsum;
    xin[h*64 + dl]    = n0*inv;
    xin[h*64 + dl+32] = n1*inv;
  }
  __syncthreads();
  size_t z0 = (size_t)vb*S_TOT*512;
  for (int n=t;n<512;n+=256){
    const float4* wr = (const float4*)(Wo + (size_t)n*512);
    float acc = bo[n];
    for (int k4=0;k4<128;k4++){
      float4 u = wr[k4]; int k=k4*4;
      acc += xin[k+0]*u.x + xin[k+1]*u.y + xin[k+2]*u.z + xin[k+3]*u.w;
    }
    y[n] = acc + bfval(Zh[z0+n]) + bfval(Zl[z0+n]);
  }
  __syncthreads();
  float s1=0.f, s2=0.f;
  for (int i=t;i<512;i+=256){ float a=y[i]; s1+=a; s2+=a*a; }
  #pragma unroll
  for (int o=32;o;o>>=1){ s1+=__shfl_down(s1,o); s2+=__shfl_down(s2,o); }
  if ((t&63)==0){ red[t>>6]=s1; red[8+(t>>6)]=s2; }
  __syncthreads();
  s1 = red[0]+red[1]+red[2]+red[3];
  s2 = red[8]+red[9]+red[10]+red[11];
  float mean = s1*(1.f/512.f);
  float var  = s2*(1.f/512.f) - mean*mean;
  float rn = rsqrtf(var + 1e-5f);
  for (int i=t;i<512;i+=256)
    clsbuf[b*1024 + branch*512 + i] = (y[i]-mean)*rn*g[i] + be[i];
}

// ---------------------------------------------------------------------------
// Final MLP layer (wave-per-neuron GEMV).
// ---------------------------------------------------------------------------
__global__ __launch_bounds__(256) void fm_layer_kernel(
    const float* __restrict__ in, const float* __restrict__ W,
    const float* __restrict__ bias, float* __restrict__ out,
    int K, int N, int act) {
  int b = blockIdx.y;
  int n = blockIdx.x*4 + (threadIdx.x >> 6);
  int lane = threadIdx.x & 63;
  __shared__ float xs[1024];
  for (int i=threadIdx.x; i<K; i+=256) xs[i] = in[(size_t)b*K + i];
  __syncthreads();
  const float* wr = W + (size_t)n*K;
  float acc = 0.f;
  #pragma unroll 4
  for (int k=lane*4; k<K; k+=256){
    float4 u = *(const float4*)(wr + k);
    acc += xs[k]*u.x + xs[k+1]*u.y + xs[k+2]*u.z + xs[k+3]*u.w;
  }
  #pragma unroll
  for (int o=32;o;o>>=1) acc += __shfl_down(acc, o);
  if (lane==0){
    float v = acc + bias[n];
    if (act) v = gelu_exact(v);
    out[(size_t)b*N + n] = v;
  }
}

// ---------------------------------------------------------------------------
extern "C" void kernel_launch(void* const* d_in, const int* in_sizes, int n_in,
                              void* d_out, int out_size, void* d_ws, size_t ws_size,
                              hipStream_t stream) {
  const float* x      = (const float*)d_in[0];
  const float* cls_tk = (const float*)d_in[1];
  const float* ln_g   = (const float*)d_in[2];
  const float* ln_b   = (const float*)d_in[3];
  const float* aw_W0  = (const float*)d_in[4];  const float* aw_b0 = (const float*)d_in[5];
  const float* aw_W1  = (const float*)d_in[6];  const float* aw_b1 = (const float*)d_in[7];
  const float* aw_W2  = (const float*)d_in[8];  const float* aw_b2 = (const float*)d_in[9];
  const float* pr_W0  = (const float*)d_in[10]; const float* pr_b0 = (const float*)d_in[11];
  const float* pr_W1  = (const float*)d_in[12]; const float* pr_b1 = (const float*)d_in[13];
  const float* pr_W2  = (const float*)d_in[14]; const float* pr_b2 = (const float*)d_in[15];
  const float* mWqkv[2] = {(const float*)d_in[16], (const float*)d_in[20]};
  const float* mbqkv[2] = {(const float*)d_in[17], (const float*)d_in[21]};
  const float* mWo[2]   = {(const float*)d_in[18], (const float*)d_in[22]};
  const float* mbo[2]   = {(const float*)d_in[19], (const float*)d_in[23]};

  float* ws = (float*)d_ws;
  size_t off = 0;
  float* weight = ws + off; off += 8192;                      // [B,N]
  int*   idx    = (int*)(ws + off); off += VROWS + 8;         // [VB,S]
  int*   cnt    = (int*)(ws + off); off += 16;                // [VB]
  float* W0T    = ws + off; off += 32768;                     // [512][64]
  const size_t HBUF = (size_t)VROWS*512/2;                    // bf16 array in float units
  unsigned short* Zh = (unsigned short*)(ws + off); off += HBUF;
  unsigned short* Zl = (unsigned short*)(ws + off); off += HBUF;
  float* QKVr   = ws + off; off += (size_t)VROWS*1536/2;      // shared region (bf16-sized):
  unsigned short* QKVb = (unsigned short*)QKVr;               //  layer-0 QKV bf16 (stride 1536)
  float* T2     = QKVr;                                       //  out-proj fp32 (stride 512)
  unsigned short* KVb  = (unsigned short*)QKVr;               //  layer-1 KV bf16 (stride 1024)
  unsigned short* Oh = (unsigned short*)(ws + off); off += HBUF;  // also a1 hi
  unsigned short* Ol = (unsigned short*)(ws + off); off += HBUF;  // also a1 lo
  unsigned short* Wq0h = (unsigned short*)(ws + off); off += 393216;
  unsigned short* Wq0l = (unsigned short*)(ws + off); off += 393216;
  unsigned short* Wq1h = (unsigned short*)(ws + off); off += 393216;
  unsigned short* Wq1l = (unsigned short*)(ws + off); off += 393216;
  unsigned short* Wo0h = (unsigned short*)(ws + off); off += 131072;
  unsigned short* Wo0l = (unsigned short*)(ws + off); off += 131072;
  float* q0buf  = ws + off; off += VB*512;                    // [VB,D]
  float* clsb   = ws + off; off += 4096;                      // [B,2D]
  float* h1buf  = ws + off; off += 2048;                      // [B,D]
  float* h2buf  = ws + off; off += 2048;                      // [B,D]
  float* partM  = ws + off; off += VB*NH*NCHUNK;              // 1024
  float* partL  = ws + off; off += VB*NH*NCHUNK;              // 1024
  float* partN  = ws + off; off += (size_t)VB*NH*NCHUNK*64;   // 65536
  (void)ws_size; (void)in_sizes; (void)n_in; (void)out_size;

  transpose_w0_kernel<<<(32768+255)/256, 256, 0, stream>>>(aw_W0, W0T);
  aw_weight_kernel<<<B_SZ*N_INST, 64, 0, stream>>>(
      x, W0T, aw_b0, aw_W1, aw_b1, aw_W2, aw_b2, weight);

  split_kernel<<<(786432+255)/256, 256, 0, stream>>>(mWqkv[0], Wq0h, Wq0l, 786432);
  split_kernel<<<(786432+255)/256, 256, 0, stream>>>(mWqkv[1], Wq1h, Wq1l, 786432);
  split_kernel<<<(262144+255)/256, 256, 0, stream>>>(mWo[0],  Wo0h, Wo0l, 262144);

  const int MT = (VROWS + 63)/64;   // 257 row tiles
  // both branches batched as vb = branch*4 + b
  compact_kernel<<<VB, 256, 0, stream>>>(weight, idx, cnt);
  build_z_kernel<<<VROWS, 256, 0, stream>>>(x, weight, cls_tk, ln_g, ln_b, idx, cnt, Zh, Zl);
  // layer 0
  mfma_gemm_kernel<<<dim3(1536/64, MT), 256, 0, stream>>>(
      Zh, Zl, Wq0h, Wq0l, mbqkv[0], QKVb, VROWS, 1536, cnt, 1);
  flash_attn_kernel<<<dim3((S_TOT+63)/64, NH, VB), 256, 0, stream>>>(QKVb, cnt, Oh, Ol);
  mfma_gemm_kernel<<<dim3(512/64, MT), 256, 0, stream>>>(
      Oh, Ol, Wo0h, Wo0l, mbo[0], T2, VROWS, 512, cnt, 0);
  add_ln_kernel<<<VROWS, 256, 0, stream>>>(Zh, Zl, T2, ln_g, ln_b, cnt, Oh, Ol); // a1 -> Oh/Ol
  // layer 1: row0 Q via fp32 GEMV; KV for all rows, bf16 (stride 1024)
  row0_q_kernel<<<dim3(128, VB), 256, 0, stream>>>(Oh, Ol, mWqkv[1], mbqkv[1], q0buf);
  mfma_gemm_kernel<<<dim3(1024/64, MT), 256, 0, stream>>>(
      Oh, Ol, Wq1h + (size_t)512*512, Wq1l + (size_t)512*512,
      mbqkv[1] + 512, KVb, VROWS, 1024, cnt, 1);
  attn_row0_part_kernel<<<dim3(NH, VB, NCHUNK), 256, 0, stream>>>(
      KVb, q0buf, cnt, partM, partL, partN);
  row0_proj_ln_kernel<<<VB, 256, 0, stream>>>(
      partM, partL, partN, mWo[1], mbo[1], Zh, Zl, ln_g, ln_b, clsb);
  // final MLP: 3 wave-per-neuron GEMV layers
  fm_layer_kernel<<<dim3(128, B_SZ), 256, 0, stream>>>(clsb,  pr_W0, pr_b0, h1buf, 1024, 512, 1);
  fm_layer_kernel<<<dim3(128, B_SZ), 256, 0, stream>>>(h1buf, pr_W1, pr_b1, h2buf,  512, 512, 1);
  fm_layer_kernel<<<dim3(128, B_SZ), 256, 0, stream>>>(h2buf, pr_W2, pr_b2, (float*)d_out, 512, 512, 0);
}